// Round 5
// baseline (94.773 us; speedup 1.0000x reference)
//
#include <hip/hip_runtime.h>
#include <hip/hip_bf16.h>

#define NN     200000
#define FEATD  64
#define BN     4096
#define DEG    32
#define PP     2048
#define EMB    64
#define EPSV   1e-8f

// ws layout (float offsets)
#define WS_SC    0          // float4[NN]  {s0,s1,s2,norm}
#define WS_MISC  800000     // [0..2]=mean_pos  [4..6]=inv_pe
#define WS_LOSS  800064     // 24 slots, stride 32 floats (128B apart)
#define WS_RF    800832     // [3][BN][EMB]

// ---------------------------------------------------------------- kernel A
// Per node n: sim = relu(feat_n @ rsimTrans); store {dot(pe_r,sim)}_r, ||sim||.
// rs staged in LDS, read with WAVE-UNIFORM addresses (broadcast: free).
// sim[64] lives in VGPRs -> 64 independent FMA chains (issue-bound, not
// latency-bound). 128-thread blocks, grid 1563 (~6 blocks/CU).
__global__ __launch_bounds__(128) void node_precompute(
    const float* __restrict__ features, const float* __restrict__ rsim,
    const float* __restrict__ pos_embs, float4* __restrict__ node_sc)
{
    __shared__ float4 rs4s[1024];        // rs[f][j] as float4 along j
    __shared__ float pe[192];
    int t = threadIdx.x;
    const float4* rsim4 = (const float4*)rsim;
    for (int idx = t; idx < 1024; idx += 128) rs4s[idx] = rsim4[idx];
    for (int idx = t; idx < 192; idx += 128) pe[idx] = pos_embs[idx];
    __syncthreads();

    int n = blockIdx.x * 128 + t;
    bool valid = (n < NN);
    const float4* fp = (const float4*)(features + (size_t)(valid ? n : 0) * FEATD);

    float sim[64];
#pragma unroll
    for (int j = 0; j < 64; ++j) sim[j] = 0.f;

    for (int f4 = 0; f4 < 16; ++f4) {    // rolled: keeps I-cache footprint small
        float4 fv = fp[f4];
#pragma unroll
        for (int j4 = 0; j4 < 16; ++j4) {
            float4 r0 = rs4s[(f4 * 4 + 0) * 16 + j4];   // uniform -> broadcast
            float4 r1 = rs4s[(f4 * 4 + 1) * 16 + j4];
            float4 r2 = rs4s[(f4 * 4 + 2) * 16 + j4];
            float4 r3 = rs4s[(f4 * 4 + 3) * 16 + j4];
            sim[4*j4+0] += fv.x*r0.x; sim[4*j4+1] += fv.x*r0.y;
            sim[4*j4+2] += fv.x*r0.z; sim[4*j4+3] += fv.x*r0.w;
            sim[4*j4+0] += fv.y*r1.x; sim[4*j4+1] += fv.y*r1.y;
            sim[4*j4+2] += fv.y*r1.z; sim[4*j4+3] += fv.y*r1.w;
            sim[4*j4+0] += fv.z*r2.x; sim[4*j4+1] += fv.z*r2.y;
            sim[4*j4+2] += fv.z*r2.z; sim[4*j4+3] += fv.z*r2.w;
            sim[4*j4+0] += fv.w*r3.x; sim[4*j4+1] += fv.w*r3.y;
            sim[4*j4+2] += fv.w*r3.z; sim[4*j4+3] += fv.w*r3.w;
        }
    }

    float s0 = 0.f, s1 = 0.f, s2 = 0.f, q = 0.f;
#pragma unroll
    for (int j = 0; j < 64; ++j) {
        float v = fmaxf(sim[j], 0.f);
        s0 += v * pe[j];
        s1 += v * pe[64 + j];
        s2 += v * pe[128 + j];
        q  += v * v;
    }
    if (valid) node_sc[n] = make_float4(s0, s1, s2, sqrtf(q));
}

// ---------------------------------------------------------------- kernel B
// pe inverse norms, mean(pos_scores) per relation, zero loss slots.
__global__ __launch_bounds__(1024) void pos_stats(
    const int* __restrict__ pos_nodes, const float4* __restrict__ node_sc,
    const float* __restrict__ pos_embs, float* __restrict__ misc,
    float* __restrict__ lossacc)
{
    __shared__ float invpe_s[3];
    __shared__ float wsum[16][3];
    int t = threadIdx.x, wv = t >> 6, lane = t & 63;

    if (t < 24) lossacc[t * 32] = 0.f;           // zero spread loss slots

    // pe norms: waves 0..2 each own one pos_emb row
    float pv = (t < 192) ? pos_embs[t] : 0.f;
    float q = pv * pv;
#pragma unroll
    for (int off = 32; off; off >>= 1) q += __shfl_down(q, off);
    if (t < 192 && lane == 0) {
        float inv = 1.f / fmaxf(sqrtf(q), EPSV);
        invpe_s[wv] = inv;
        misc[4 + wv] = inv;
    }
    __syncthreads();

    float i0 = invpe_s[0], i1 = invpe_s[1], i2 = invpe_s[2];
    float s0 = 0.f, s1 = 0.f, s2 = 0.f;
    for (int p = t; p < PP; p += 1024) {
        int n = pos_nodes[p];
        float4 sc = node_sc[n];
        float invn = 1.f / fmaxf(sc.w, EPSV);
        s0 += sc.x * i0 * invn;
        s1 += sc.y * i1 * invn;
        s2 += sc.z * i2 * invn;
    }
#pragma unroll
    for (int off = 32; off; off >>= 1) {
        s0 += __shfl_down(s0, off);
        s1 += __shfl_down(s1, off);
        s2 += __shfl_down(s2, off);
    }
    if (lane == 0) { wsum[wv][0] = s0; wsum[wv][1] = s1; wsum[wv][2] = s2; }
    __syncthreads();
    if (t < 3) {
        float s = 0.f;
        for (int w = 0; w < 16; ++w) s += wsum[w][t];
        misc[t] = s / (float)PP;
    }
}

// ---------------------------------------------------------------- kernel C
// One wave per (b, r): score 32 neighbors, stable top-k, parallel 16-row
// feature aggregate (4 independent dwordx4 loads), rfeat = relu(agg @ W_r).
__global__ __launch_bounds__(256) void relation_agg(
    const int* __restrict__ n1, const int* __restrict__ n2, const int* __restrict__ n3,
    const float* __restrict__ features, const float4* __restrict__ node_sc,
    const float* __restrict__ W1, const float* __restrict__ W2, const float* __restrict__ W3,
    const float* __restrict__ misc, float* __restrict__ lossacc,
    float* __restrict__ rfeat, const int* __restrict__ smp)
{
    int r = blockIdx.y;
    const int*   neigh = (r == 0) ? n1 : (r == 1) ? n2 : n3;
    const float* W     = (r == 0) ? W1 : (r == 1) ? W2 : W3;
    int k = smp[0];
    int t = threadIdx.x;
    int wv = t >> 6, lane = t & 63;
    int b = blockIdx.x * 4 + wv;
    float inv_pe   = misc[4 + r];
    float mean_pos = misc[r];

    __shared__ int sel_ids[4][32];

    // ---- score phase (lanes 0-31)
    float s = -1e30f;
    int   n = 0;
    if (lane < 32) {
        n = neigh[b * DEG + lane];
        float4 sc = node_sc[n];
        float num = (r == 0) ? sc.x : (r == 1) ? sc.y : sc.z;
        s = num * inv_pe / fmaxf(sc.w, EPSV);
    }
    // stable rank among 32 scores (ties -> lower index), matches lax.top_k
    int cnt = 0;
#pragma unroll
    for (int d2 = 0; d2 < 32; ++d2) {
        float v = __shfl(s, d2);
        cnt += ((v > s) || (v == s && d2 < lane)) ? 1 : 0;
    }
    bool sel = (lane < 32) && (cnt < k);
    if (sel) sel_ids[wv][cnt] = n;       // rank = unique slot in [0,k)

    float lv = sel ? (s - mean_pos) * (s - mean_pos) : 0.f;
#pragma unroll
    for (int off = 32; off; off >>= 1) lv += __shfl_down(lv, off);
    if (lane == 0)
        atomicAdd(&lossacc[(r * 8 + (blockIdx.x & 7)) * 32], lv);
    // no __syncthreads: sel_ids producer/consumer are the same wave (lgkmcnt)

    // ---- aggregate phase: 16 lanes per row, 4 rows per load wavefront
    const float4* F = (const float4*)features;
    int col   = lane & 15;           // float4 index within a 64-float row
    int rbase = lane >> 4;           // 0..3
    float4 a = make_float4(0.f, 0.f, 0.f, 0.f);
    if (k == 16) {
        int nid0 = sel_ids[wv][rbase];
        int nid1 = sel_ids[wv][rbase + 4];
        int nid2 = sel_ids[wv][rbase + 8];
        int nid3 = sel_ids[wv][rbase + 12];
        float4 v0 = F[(size_t)nid0 * 16 + col];
        float4 v1 = F[(size_t)nid1 * 16 + col];
        float4 v2 = F[(size_t)nid2 * 16 + col];
        float4 v3 = F[(size_t)nid3 * 16 + col];
        a.x = v0.x + v1.x + v2.x + v3.x;
        a.y = v0.y + v1.y + v2.y + v3.y;
        a.z = v0.z + v1.z + v2.z + v3.z;
        a.w = v0.w + v1.w + v2.w + v3.w;
    } else {
        for (int row0 = 0; row0 < k; row0 += 4) {
            int row = row0 + rbase;
            if (row < k) {
                int nid = sel_ids[wv][row];
                float4 v = F[(size_t)nid * 16 + col];
                a.x += v.x; a.y += v.y; a.z += v.z; a.w += v.w;
            }
        }
    }
    // allreduce across the 4 row-groups (xor 16, 32)
#pragma unroll
    for (int off = 16; off <= 32; off <<= 1) {
        a.x += __shfl_xor(a.x, off);
        a.y += __shfl_xor(a.y, off);
        a.z += __shfl_xor(a.z, off);
        a.w += __shfl_xor(a.w, off);
    }
    float inv_k = 1.f / (float)k;
    a.x *= inv_k; a.y *= inv_k; a.z *= inv_k; a.w *= inv_k;
    // lane l holds agg[cols (l&15)*4 .. +4], replicated across l>>4

    // ---- rfeat[e=lane] = relu(sum_j agg[j] * W[j][e])
    float acc = 0.f;
#pragma unroll
    for (int j4 = 0; j4 < 16; ++j4) {
        float a0 = __shfl(a.x, j4);
        float a1 = __shfl(a.y, j4);
        float a2 = __shfl(a.z, j4);
        float a3 = __shfl(a.w, j4);
        acc += a0 * W[(j4 * 4 + 0) * EMB + lane]
             + a1 * W[(j4 * 4 + 1) * EMB + lane]
             + a2 * W[(j4 * 4 + 2) * EMB + lane]
             + a3 * W[(j4 * 4 + 3) * EMB + lane];
    }
    rfeat[((size_t)r * BN + b) * EMB + lane] = fmaxf(acc, 0.f);
}

// ---------------------------------------------------------------- kernel D
// combined[e][b] = relu(cat[b] . weight[:,e]).
// 512 blocks, b-tile = 8. weight read from GLOBAL, coalesced (lane = e,
// row stride 256B) — 16KB table stays L1-resident; cat in LDS (uniform
// broadcast reads). No wgtT LDS (old version had 8-way bank conflicts).
#define CSTRIDE 264
__global__ __launch_bounds__(256) void final_mm(
    const int* __restrict__ nodes, const float* __restrict__ features,
    const float* __restrict__ rfeat, const float* __restrict__ weight,
    const float* __restrict__ lossacc, const int* __restrict__ smp,
    float* __restrict__ out)
{
    __shared__ float cat_b[8 * CSTRIDE];   // cat_b[bb][i]
    __shared__ float trans[8 * 65];        // output transpose tile
    __shared__ float ls[24];
    int t = threadIdx.x;
    int b0 = blockIdx.x * 8;

    if (blockIdx.x == 0 && t < 24) ls[t] = lossacc[t * 32];

    // stage cat columns: center features then 3 rfeat blocks
    for (int idx = t; idx < 512; idx += 256) {
        int bb = idx >> 6, f = idx & 63;
        cat_b[bb * CSTRIDE + f] = features[(size_t)nodes[b0 + bb] * FEATD + f];
    }
#pragma unroll
    for (int r = 0; r < 3; ++r)
        for (int idx = t; idx < 512; idx += 256) {
            int bb = idx >> 6, j = idx & 63;
            cat_b[bb * CSTRIDE + 64 + r * 64 + j] =
                rfeat[((size_t)r * BN + b0 + bb) * EMB + j];
        }
    __syncthreads();

    int wv = t >> 6, lane = t & 63;     // lane = e
    int bb0 = wv * 2;
    float acc0 = 0.f, acc1 = 0.f;
    const float* c0p = &cat_b[bb0 * CSTRIDE];
    const float* c1p = &cat_b[(bb0 + 1) * CSTRIDE];
    for (int i0 = 0; i0 < 256; i0 += 16) {
        float w[16];
#pragma unroll
        for (int u = 0; u < 16; ++u)
            w[u] = weight[(i0 + u) * EMB + lane];   // coalesced, L1-hot, 16 in flight
#pragma unroll
        for (int u = 0; u < 16; ++u) {
            acc0 += w[u] * c0p[i0 + u];             // uniform LDS broadcast
            acc1 += w[u] * c1p[i0 + u];
        }
    }
    trans[bb0 * 65 + lane]       = fmaxf(acc0, 0.f);
    trans[(bb0 + 1) * 65 + lane] = fmaxf(acc1, 0.f);
    __syncthreads();

    // store: out[e][b0..b0+8]
    for (int idx = t; idx < 512; idx += 256) {
        int e = idx >> 3, bb = idx & 7;
        out[(size_t)e * BN + b0 + bb] = trans[bb * 65 + e];
    }

    if (blockIdx.x == 0 && t == 0) {
        int k = smp[0];
        float s = 0.f;
        for (int i = 0; i < 24; ++i) s += ls[i];
        out[(size_t)EMB * BN] = s / (3.f * (float)BN * (float)k);
    }
}

// ----------------------------------------------------------------
extern "C" void kernel_launch(void* const* d_in, const int* in_sizes, int n_in,
                              void* d_out, int out_size, void* d_ws, size_t ws_size,
                              hipStream_t stream) {
    const int*   nodes     = (const int*)  d_in[0];
    // d_in[1] labels: unused
    const int*   neigh1    = (const int*)  d_in[2];
    const int*   neigh2    = (const int*)  d_in[3];
    const int*   neigh3    = (const int*)  d_in[4];
    const int*   pos_nodes = (const int*)  d_in[5];
    const float* features  = (const float*)d_in[6];
    const float* weight    = (const float*)d_in[7];
    const float* rsim      = (const float*)d_in[8];
    const float* pos_embs  = (const float*)d_in[9];
    const float* W1        = (const float*)d_in[10];
    const float* W2        = (const float*)d_in[11];
    const float* W3        = (const float*)d_in[12];
    const int*   smp       = (const int*)  d_in[13];
    float* out = (float*)d_out;
    float* ws  = (float*)d_ws;

    float4* node_sc = (float4*)(ws + WS_SC);
    float*  misc    = ws + WS_MISC;
    float*  lossacc = ws + WS_LOSS;
    float*  rfeat   = ws + WS_RF;

    node_precompute<<<dim3((NN + 127) / 128), dim3(128), 0, stream>>>(
        features, rsim, pos_embs, node_sc);
    pos_stats<<<dim3(1), dim3(1024), 0, stream>>>(
        pos_nodes, node_sc, pos_embs, misc, lossacc);
    relation_agg<<<dim3(BN / 4, 3), dim3(256), 0, stream>>>(
        neigh1, neigh2, neigh3, features, node_sc, W1, W2, W3,
        misc, lossacc, rfeat, smp);
    final_mm<<<dim3(BN / 8), dim3(256), 0, stream>>>(
        nodes, features, rfeat, weight, lossacc, smp, out);
}

// Round 6
// 91.199 us; speedup vs baseline: 1.0392x; 1.0392x over previous
//
#include <hip/hip_runtime.h>
#include <hip/hip_bf16.h>

#define NN     200000
#define FEATD  64
#define BN     4096
#define DEG    32
#define PP     2048
#define EMB    64
#define EPSV   1e-8f

// ws layout (float offsets)
#define WS_SC    0          // float4[NN]  {s0,s1,s2,norm}
#define WS_MISC  800000     // [0..2]=mean_pos  [4..6]=inv_pe
#define WS_LOSS  800064     // 24 slots, stride 32 floats (128B apart)
#define WS_RF    800832     // [3][BN][EMB]

typedef float sfv16 __attribute__((ext_vector_type(16)));

// Forced scalar load: 32 floats -> 32 SGPRs. Load+wait fused in one asm block;
// consumers depend on the "=s" outputs so ordering is data-dependence-safe.
__device__ __forceinline__ void sload32(const float* p, sfv16& a, sfv16& b) {
    asm volatile("s_load_dwordx16 %0, %2, 0x0\n\t"
                 "s_load_dwordx16 %1, %2, 0x40\n\t"
                 "s_waitcnt lgkmcnt(0)"
                 : "=s"(a), "=s"(b) : "s"(p));
}

// ---------------------------------------------------------------- kernel A
// Per node n: sim = relu(feat_n @ rsimTrans); store {dot(pe_r,sim)}_r, ||sim||.
// rsim/pos_embs consumed via SGPR s_load_dwordx16 (scalar pipe) ->
// v_fma_f32 vD, sS, vV. Zero LDS, zero shuffles. sim[64] = 64 independent
// VGPR accumulator chains. grid*block == NN exactly.
__global__ __launch_bounds__(64) void node_precompute(
    const float* __restrict__ features, const float* __restrict__ rsim,
    const float* __restrict__ pos_embs, float4* __restrict__ node_sc)
{
    int n = blockIdx.x * 64 + threadIdx.x;
    const float4* fp = (const float4*)(features + (size_t)n * FEATD);

    float sim[64];
#pragma unroll
    for (int j = 0; j < 64; ++j) sim[j] = 0.f;

    for (int f4 = 0; f4 < 16; ++f4) {          // rolled outer loop
        float4 fvv = fp[f4];                   // per-lane feature quad (vmcnt)
#pragma unroll
        for (int u = 0; u < 4; ++u) {          // static -> sim[] stays in VGPRs
            float x = (u == 0) ? fvv.x : (u == 1) ? fvv.y
                    : (u == 2) ? fvv.z : fvv.w;
            const float* row = rsim + (f4 * 4 + u) * 64;
            sfv16 a, b;
            sload32(row, a, b);
#pragma unroll
            for (int j = 0; j < 16; ++j) sim[j]      += x * a[j];
#pragma unroll
            for (int j = 0; j < 16; ++j) sim[16 + j] += x * b[j];
            sfv16 c, d;
            sload32(row + 32, c, d);
#pragma unroll
            for (int j = 0; j < 16; ++j) sim[32 + j] += x * c[j];
#pragma unroll
            for (int j = 0; j < 16; ++j) sim[48 + j] += x * d[j];
        }
    }

    float q = 0.f;
#pragma unroll
    for (int j = 0; j < 64; ++j) {
        float v = fmaxf(sim[j], 0.f);
        sim[j] = v;
        q += v * v;
    }

    float sc0 = 0.f, sc1 = 0.f, sc2 = 0.f;
#pragma unroll
    for (int r = 0; r < 3; ++r) {
        sfv16 a, b, c, d;
        sload32(pos_embs + r * 64, a, b);
        sload32(pos_embs + r * 64 + 32, c, d);
        float acc = 0.f;
#pragma unroll
        for (int j = 0; j < 16; ++j) acc += sim[j]      * a[j];
#pragma unroll
        for (int j = 0; j < 16; ++j) acc += sim[16 + j] * b[j];
#pragma unroll
        for (int j = 0; j < 16; ++j) acc += sim[32 + j] * c[j];
#pragma unroll
        for (int j = 0; j < 16; ++j) acc += sim[48 + j] * d[j];
        if (r == 0) sc0 = acc; else if (r == 1) sc1 = acc; else sc2 = acc;
    }
    node_sc[n] = make_float4(sc0, sc1, sc2, sqrtf(q));
}

// ---------------------------------------------------------------- kernel B
// pe inverse norms, mean(pos_scores) per relation, zero loss slots.
__global__ __launch_bounds__(1024) void pos_stats(
    const int* __restrict__ pos_nodes, const float4* __restrict__ node_sc,
    const float* __restrict__ pos_embs, float* __restrict__ misc,
    float* __restrict__ lossacc)
{
    __shared__ float invpe_s[3];
    __shared__ float wsum[16][3];
    int t = threadIdx.x, wv = t >> 6, lane = t & 63;

    if (t < 24) lossacc[t * 32] = 0.f;           // zero spread loss slots

    // pe norms: waves 0..2 each own one pos_emb row
    float pv = (t < 192) ? pos_embs[t] : 0.f;
    float q = pv * pv;
#pragma unroll
    for (int off = 32; off; off >>= 1) q += __shfl_down(q, off);
    if (t < 192 && lane == 0) {
        float inv = 1.f / fmaxf(sqrtf(q), EPSV);
        invpe_s[wv] = inv;
        misc[4 + wv] = inv;
    }
    __syncthreads();

    float i0 = invpe_s[0], i1 = invpe_s[1], i2 = invpe_s[2];
    float s0 = 0.f, s1 = 0.f, s2 = 0.f;
    for (int p = t; p < PP; p += 1024) {
        int n = pos_nodes[p];
        float4 sc = node_sc[n];
        float invn = 1.f / fmaxf(sc.w, EPSV);
        s0 += sc.x * i0 * invn;
        s1 += sc.y * i1 * invn;
        s2 += sc.z * i2 * invn;
    }
#pragma unroll
    for (int off = 32; off; off >>= 1) {
        s0 += __shfl_down(s0, off);
        s1 += __shfl_down(s1, off);
        s2 += __shfl_down(s2, off);
    }
    if (lane == 0) { wsum[wv][0] = s0; wsum[wv][1] = s1; wsum[wv][2] = s2; }
    __syncthreads();
    if (t < 3) {
        float s = 0.f;
        for (int w = 0; w < 16; ++w) s += wsum[w][t];
        misc[t] = s / (float)PP;
    }
}

// ---------------------------------------------------------------- kernel C
// One wave per (b, r): score 32 neighbors, stable top-k, parallel 16-row
// feature aggregate, rfeat = relu(agg @ W_r). W-phase broadcast via LDS
// uniform reads (16 b128) instead of 64 ds_bpermute shuffles.
__global__ __launch_bounds__(256) void relation_agg(
    const int* __restrict__ n1, const int* __restrict__ n2, const int* __restrict__ n3,
    const float* __restrict__ features, const float4* __restrict__ node_sc,
    const float* __restrict__ W1, const float* __restrict__ W2, const float* __restrict__ W3,
    const float* __restrict__ misc, float* __restrict__ lossacc,
    float* __restrict__ rfeat, const int* __restrict__ smp)
{
    int r = blockIdx.y;
    const int*   neigh = (r == 0) ? n1 : (r == 1) ? n2 : n3;
    const float* W     = (r == 0) ? W1 : (r == 1) ? W2 : W3;
    int k = smp[0];
    int t = threadIdx.x;
    int wv = t >> 6, lane = t & 63;
    int b = blockIdx.x * 4 + wv;
    float inv_pe   = misc[4 + r];
    float mean_pos = misc[r];

    __shared__ int sel_ids[4][32];
    __shared__ float4 aggl[4][16];

    // ---- score phase (lanes 0-31)
    float s = -1e30f;
    int   n = 0;
    if (lane < 32) {
        n = neigh[b * DEG + lane];
        float4 sc = node_sc[n];
        float num = (r == 0) ? sc.x : (r == 1) ? sc.y : sc.z;
        s = num * inv_pe / fmaxf(sc.w, EPSV);
    }
    // stable rank among 32 scores (ties -> lower index), matches lax.top_k
    int cnt = 0;
#pragma unroll
    for (int d2 = 0; d2 < 32; ++d2) {
        float v = __shfl(s, d2);
        cnt += ((v > s) || (v == s && d2 < lane)) ? 1 : 0;
    }
    bool sel = (lane < 32) && (cnt < k);
    if (sel) sel_ids[wv][cnt] = n;       // rank = unique slot in [0,k)

    float lv = sel ? (s - mean_pos) * (s - mean_pos) : 0.f;
#pragma unroll
    for (int off = 32; off; off >>= 1) lv += __shfl_down(lv, off);
    if (lane == 0)
        atomicAdd(&lossacc[(r * 8 + (blockIdx.x & 7)) * 32], lv);
    // no __syncthreads: sel_ids producer/consumer are the same wave (lgkmcnt)

    // ---- aggregate phase: 16 lanes per row, 4 rows per load wavefront
    const float4* F = (const float4*)features;
    int col   = lane & 15;           // float4 index within a 64-float row
    int rbase = lane >> 4;           // 0..3
    float4 a = make_float4(0.f, 0.f, 0.f, 0.f);
    if (k == 16) {
        int nid0 = sel_ids[wv][rbase];
        int nid1 = sel_ids[wv][rbase + 4];
        int nid2 = sel_ids[wv][rbase + 8];
        int nid3 = sel_ids[wv][rbase + 12];
        float4 v0 = F[(size_t)nid0 * 16 + col];
        float4 v1 = F[(size_t)nid1 * 16 + col];
        float4 v2 = F[(size_t)nid2 * 16 + col];
        float4 v3 = F[(size_t)nid3 * 16 + col];
        a.x = v0.x + v1.x + v2.x + v3.x;
        a.y = v0.y + v1.y + v2.y + v3.y;
        a.z = v0.z + v1.z + v2.z + v3.z;
        a.w = v0.w + v1.w + v2.w + v3.w;
    } else {
        for (int row0 = 0; row0 < k; row0 += 4) {
            int row = row0 + rbase;
            if (row < k) {
                int nid = sel_ids[wv][row];
                float4 v = F[(size_t)nid * 16 + col];
                a.x += v.x; a.y += v.y; a.z += v.z; a.w += v.w;
            }
        }
    }
    // allreduce across the 4 row-groups (xor 16, 32)
#pragma unroll
    for (int off = 16; off <= 32; off <<= 1) {
        a.x += __shfl_xor(a.x, off);
        a.y += __shfl_xor(a.y, off);
        a.z += __shfl_xor(a.z, off);
        a.w += __shfl_xor(a.w, off);
    }
    float inv_k = 1.f / (float)k;
    a.x *= inv_k; a.y *= inv_k; a.z *= inv_k; a.w *= inv_k;

    // publish agg to LDS (lanes 0-15 hold cols 0..15 replicated-free)
    if (lane < 16) aggl[wv][lane] = a;
    // same-wave producer/consumer: compiler inserts lgkmcnt, no barrier

    // ---- rfeat[e=lane] = relu(sum_j agg[j] * W[j][e]) via uniform LDS reads
    float acc = 0.f;
#pragma unroll
    for (int j4 = 0; j4 < 16; ++j4) {
        float4 ag = aggl[wv][j4];            // wave-uniform -> broadcast
        acc += ag.x * W[(j4 * 4 + 0) * EMB + lane]
             + ag.y * W[(j4 * 4 + 1) * EMB + lane]
             + ag.z * W[(j4 * 4 + 2) * EMB + lane]
             + ag.w * W[(j4 * 4 + 3) * EMB + lane];
    }
    rfeat[((size_t)r * BN + b) * EMB + lane] = fmaxf(acc, 0.f);
}

// ---------------------------------------------------------------- kernel D
// combined[e][b] = relu(cat[b] . weight[:,e]).
// 512 blocks, b-tile = 8. weight read from GLOBAL, coalesced (lane = e,
// row stride 256B) — 16KB table L1-resident; cat in LDS (uniform broadcast).
#define CSTRIDE 264
__global__ __launch_bounds__(256) void final_mm(
    const int* __restrict__ nodes, const float* __restrict__ features,
    const float* __restrict__ rfeat, const float* __restrict__ weight,
    const float* __restrict__ lossacc, const int* __restrict__ smp,
    float* __restrict__ out)
{
    __shared__ float cat_b[8 * CSTRIDE];   // cat_b[bb][i]
    __shared__ float trans[8 * 65];        // output transpose tile
    __shared__ float ls[24];
    int t = threadIdx.x;
    int b0 = blockIdx.x * 8;

    if (blockIdx.x == 0 && t < 24) ls[t] = lossacc[t * 32];

    // stage cat columns: center features then 3 rfeat blocks
    for (int idx = t; idx < 512; idx += 256) {
        int bb = idx >> 6, f = idx & 63;
        cat_b[bb * CSTRIDE + f] = features[(size_t)nodes[b0 + bb] * FEATD + f];
    }
#pragma unroll
    for (int r = 0; r < 3; ++r)
        for (int idx = t; idx < 512; idx += 256) {
            int bb = idx >> 6, j = idx & 63;
            cat_b[bb * CSTRIDE + 64 + r * 64 + j] =
                rfeat[((size_t)r * BN + b0 + bb) * EMB + j];
        }
    __syncthreads();

    int wv = t >> 6, lane = t & 63;     // lane = e
    int bb0 = wv * 2;
    float acc0 = 0.f, acc1 = 0.f;
    const float* c0p = &cat_b[bb0 * CSTRIDE];
    const float* c1p = &cat_b[(bb0 + 1) * CSTRIDE];
    for (int i0 = 0; i0 < 256; i0 += 16) {
        float w[16];
#pragma unroll
        for (int u = 0; u < 16; ++u)
            w[u] = weight[(i0 + u) * EMB + lane];   // coalesced, L1-hot
#pragma unroll
        for (int u = 0; u < 16; ++u) {
            acc0 += w[u] * c0p[i0 + u];             // uniform LDS broadcast
            acc1 += w[u] * c1p[i0 + u];
        }
    }
    trans[bb0 * 65 + lane]       = fmaxf(acc0, 0.f);
    trans[(bb0 + 1) * 65 + lane] = fmaxf(acc1, 0.f);
    __syncthreads();

    // store: out[e][b0..b0+8]
    for (int idx = t; idx < 512; idx += 256) {
        int e = idx >> 3, bb = idx & 7;
        out[(size_t)e * BN + b0 + bb] = trans[bb * 65 + e];
    }

    if (blockIdx.x == 0 && t == 0) {
        int k = smp[0];
        float s = 0.f;
        for (int i = 0; i < 24; ++i) s += ls[i];
        out[(size_t)EMB * BN] = s / (3.f * (float)BN * (float)k);
    }
}

// ----------------------------------------------------------------
extern "C" void kernel_launch(void* const* d_in, const int* in_sizes, int n_in,
                              void* d_out, int out_size, void* d_ws, size_t ws_size,
                              hipStream_t stream) {
    const int*   nodes     = (const int*)  d_in[0];
    // d_in[1] labels: unused
    const int*   neigh1    = (const int*)  d_in[2];
    const int*   neigh2    = (const int*)  d_in[3];
    const int*   neigh3    = (const int*)  d_in[4];
    const int*   pos_nodes = (const int*)  d_in[5];
    const float* features  = (const float*)d_in[6];
    const float* weight    = (const float*)d_in[7];
    const float* rsim      = (const float*)d_in[8];
    const float* pos_embs  = (const float*)d_in[9];
    const float* W1        = (const float*)d_in[10];
    const float* W2        = (const float*)d_in[11];
    const float* W3        = (const float*)d_in[12];
    const int*   smp       = (const int*)  d_in[13];
    float* out = (float*)d_out;
    float* ws  = (float*)d_ws;

    float4* node_sc = (float4*)(ws + WS_SC);
    float*  misc    = ws + WS_MISC;
    float*  lossacc = ws + WS_LOSS;
    float*  rfeat   = ws + WS_RF;

    node_precompute<<<dim3(NN / 64), dim3(64), 0, stream>>>(
        features, rsim, pos_embs, node_sc);
    pos_stats<<<dim3(1), dim3(1024), 0, stream>>>(
        pos_nodes, node_sc, pos_embs, misc, lossacc);
    relation_agg<<<dim3(BN / 4, 3), dim3(256), 0, stream>>>(
        neigh1, neigh2, neigh3, features, node_sc, W1, W2, W3,
        misc, lossacc, rfeat, smp);
    final_mm<<<dim3(BN / 8), dim3(256), 0, stream>>>(
        nodes, features, rfeat, weight, lossacc, smp, out);
}